// Round 9
// baseline (405.000 us; speedup 1.0000x reference)
//
#include <hip/hip_runtime.h>
#include <hip/hip_fp16.h>
#include <math.h>

#define N_NODES 100000
#define N_EDGES 1600000
#define F 128
#define NBUK 196        // ceil(N_NODES / 512)
#define BSH 9           // bucket = node >> 9  (512 nodes per bucket)
#define BSZ 512

typedef _Float16 half8 __attribute__((ext_vector_type(8)));
typedef float    f32x4 __attribute__((ext_vector_type(4)));

// ---------------------------------------------------------------- K1: bucket totals
__global__ __launch_bounds__(256) void hist_buckets(const int* __restrict__ src,
                                                    const int* __restrict__ dst,
                                                    int* __restrict__ totD,
                                                    int* __restrict__ totS)
{
    __shared__ int hd[NBUK], hs[NBUK];
    const int tid = threadIdx.x;
    if (tid < NBUK) { hd[tid] = 0; hs[tid] = 0; }
    __syncthreads();
    const int nt = gridDim.x * 256;
    const int n4 = N_EDGES / 4;
    for (int i = blockIdx.x * 256 + tid; i < n4; i += nt) {
        int4 d = reinterpret_cast<const int4*>(dst)[i];
        int4 s = reinterpret_cast<const int4*>(src)[i];
        atomicAdd(&hd[d.x >> BSH], 1); atomicAdd(&hd[d.y >> BSH], 1);
        atomicAdd(&hd[d.z >> BSH], 1); atomicAdd(&hd[d.w >> BSH], 1);
        atomicAdd(&hs[s.x >> BSH], 1); atomicAdd(&hs[s.y >> BSH], 1);
        atomicAdd(&hs[s.z >> BSH], 1); atomicAdd(&hs[s.w >> BSH], 1);
    }
    __syncthreads();
    if (tid < NBUK) {
        if (hd[tid]) atomicAdd(&totD[tid], hd[tid]);
        if (hs[tid]) atomicAdd(&totS[tid], hs[tid]);
    }
}

// ---------------------------------------------------------------- K2: scan totals
__global__ __launch_bounds__(256) void scan_buckets(const int* __restrict__ totD,
                                                    const int* __restrict__ totS,
                                                    int* __restrict__ baseD,
                                                    int* __restrict__ baseS,
                                                    int* __restrict__ curD,
                                                    int* __restrict__ curS)
{
    __shared__ int sd[256], ss[256];
    const int t = threadIdx.x;
    int vd = (t < NBUK) ? totD[t] : 0;
    int vs = (t < NBUK) ? totS[t] : 0;
    sd[t] = vd; ss[t] = vs;
    __syncthreads();
    for (int off = 1; off < 256; off <<= 1) {
        int ud = (t >= off) ? sd[t - off] : 0;
        int us = (t >= off) ? ss[t - off] : 0;
        __syncthreads();
        sd[t] += ud; ss[t] += us;
        __syncthreads();
    }
    if (t < NBUK) {
        baseD[t] = sd[t] - vd; curD[t] = sd[t] - vd;
        baseS[t] = ss[t] - vs; curS[t] = ss[t] - vs;
    }
    if (t == NBUK - 1) { baseD[NBUK] = sd[t]; baseS[NBUK] = ss[t]; }
}

// ---------------------------------------------------------------- K3: partition
__global__ __launch_bounds__(512) void partition(const int* __restrict__ src,
                                                 const int* __restrict__ dst,
                                                 int* __restrict__ curD,
                                                 int* __restrict__ curS,
                                                 int2* __restrict__ bukD,
                                                 int* __restrict__ bukS)
{
    __shared__ int hd[NBUK], hs[NBUK], bd[NBUK], bs[NBUK], cd[NBUK], cs[NBUK];
    const int tid = threadIdx.x;
    const int chunk = (N_EDGES + gridDim.x - 1) / gridDim.x;
    const int beg = blockIdx.x * chunk;
    const int end = min(beg + chunk, N_EDGES);
    if (tid < NBUK) { hd[tid] = 0; hs[tid] = 0; cd[tid] = 0; cs[tid] = 0; }
    __syncthreads();
    for (int e = beg + tid; e < end; e += 512) {
        atomicAdd(&hd[dst[e] >> BSH], 1);
        atomicAdd(&hs[src[e] >> BSH], 1);
    }
    __syncthreads();
    if (tid < NBUK) {
        bd[tid] = hd[tid] ? atomicAdd(&curD[tid], hd[tid]) : 0;
        bs[tid] = hs[tid] ? atomicAdd(&curS[tid], hs[tid]) : 0;
    }
    __syncthreads();
    for (int e = beg + tid; e < end; e += 512) {
        int d = dst[e], s = src[e];
        int bin = d >> BSH;
        int r = atomicAdd(&cd[bin], 1);
        bukD[bd[bin] + r] = make_int2(d, s);
        int bin2 = s >> BSH;
        int r2 = atomicAdd(&cs[bin2], 1);
        bukS[bs[bin2] + r2] = s;
    }
}

// ---------------------------------------------------------------- K4: per-bucket CSR
__global__ __launch_bounds__(512) void csr_bucket(const int2* __restrict__ bukD,
                                                  const int* __restrict__ baseD,
                                                  int* __restrict__ row_ptr,
                                                  float* __restrict__ sin_,
                                                  int* __restrict__ col)
{
    __shared__ int h[BSZ], sc[BSZ], cur[BSZ];
    const int tid = threadIdx.x;
    const int n0 = blockIdx.x << BSH;
    const int lo = baseD[blockIdx.x], hi = baseD[blockIdx.x + 1];
    h[tid] = 0;
    __syncthreads();
    for (int i = lo + tid; i < hi; i += 512)
        atomicAdd(&h[bukD[i].x - n0], 1);
    __syncthreads();
    int own = h[tid];
    sc[tid] = own;
    __syncthreads();
    for (int off = 1; off < 512; off <<= 1) {
        int u = (tid >= off) ? sc[tid - off] : 0;
        __syncthreads();
        sc[tid] += u;
        __syncthreads();
    }
    int ex = sc[tid] - own;
    cur[tid] = ex;
    int node = n0 + tid;
    if (node <= N_NODES) row_ptr[node] = lo + ex;
    if (node < N_NODES)  sin_[node] = rsqrtf((float)max(own, 1));
    __syncthreads();
    for (int i = lo + tid; i < hi; i += 512) {
        int2 p = bukD[i];
        int r = atomicAdd(&cur[p.x - n0], 1);
        col[lo + r] = p.y;
    }
}

// ---------------------------------------------------------------- K5: out-degree
__global__ __launch_bounds__(512) void deg_bucket(const int* __restrict__ bukS,
                                                  const int* __restrict__ baseS,
                                                  float* __restrict__ sout)
{
    __shared__ int h[BSZ];
    const int tid = threadIdx.x;
    const int n0 = blockIdx.x << BSH;
    const int lo = baseS[blockIdx.x], hi = baseS[blockIdx.x + 1];
    h[tid] = 0;
    __syncthreads();
    for (int i = lo + tid; i < hi; i += 512)
        atomicAdd(&h[bukS[i] - n0], 1);
    __syncthreads();
    int node = n0 + tid;
    if (node < N_NODES) sout[node] = rsqrtf((float)max(h[tid], 1));
}

// ---------------------------------------------------------------- pack W into B-fragment order (hi/lo fp16)
__global__ __launch_bounds__(256) void pack_w(const float* __restrict__ W,
                                              _Float16* __restrict__ hi,
                                              _Float16* __restrict__ lo)
{
    int idx = blockIdx.x * 256 + threadIdx.x;
    if (idx >= 16384) return;
    int f = idx >> 9, r = idx & 511;
    int l = r >> 3, j = r & 7;
    int kc = f >> 3, ct = f & 7;
    int k = kc * 32 + (l >> 4) * 8 + j;
    int n = ct * 16 + (l & 15);
    float w = W[k * 128 + n];
    _Float16 h = (_Float16)w;
    hi[idx] = h;
    lo[idx] = (_Float16)(w - (float)h);
}

// ---------------------------------------------------------------- MFMA GEMM, fp32 input (split hi/lo: 3 terms)
__global__ __launch_bounds__(256) void gemm_mfma_f32(const float* __restrict__ X,
                                                     const _Float16* __restrict__ Whi,
                                                     const _Float16* __restrict__ Wlo,
                                                     const float* __restrict__ srow,
                                                     _Float16* __restrict__ Y, int N)
{
    const int tid = threadIdx.x;
    const int l = tid & 63, w = tid >> 6;
    const int quad = l >> 4, m = l & 15;
    const int row0 = blockIdx.x * 128;
    const half8* Bh = reinterpret_cast<const half8*>(Whi);
    const half8* Bl = reinterpret_cast<const half8*>(Wlo);

    f32x4 acc[2][8] = {};

    for (int kc = 0; kc < 4; kc++) {
        half8 ah[2], al[2];
        #pragma unroll
        for (int rt = 0; rt < 2; rt++) {
            int grow = row0 + w * 32 + rt * 16 + m;
            float4 xa = make_float4(0.f, 0.f, 0.f, 0.f), xb = xa;
            if (grow < N) {
                const float4* Xp = reinterpret_cast<const float4*>(X) + (size_t)grow * 32 + kc * 8 + quad * 2;
                xa = Xp[0]; xb = Xp[1];
            }
            float xs[8] = {xa.x, xa.y, xa.z, xa.w, xb.x, xb.y, xb.z, xb.w};
            #pragma unroll
            for (int j = 0; j < 8; j++) {
                _Float16 h = (_Float16)xs[j];
                ah[rt][j] = h;
                al[rt][j] = (_Float16)(xs[j] - (float)h);
            }
        }
        #pragma unroll
        for (int ct = 0; ct < 8; ct++) {
            int f = kc * 8 + ct;
            half8 bh = Bh[f * 64 + l];
            half8 bl = Bl[f * 64 + l];
            #pragma unroll
            for (int rt = 0; rt < 2; rt++) {
                acc[rt][ct] = __builtin_amdgcn_mfma_f32_16x16x32_f16(ah[rt], bh, acc[rt][ct], 0, 0, 0);
                acc[rt][ct] = __builtin_amdgcn_mfma_f32_16x16x32_f16(al[rt], bh, acc[rt][ct], 0, 0, 0);
                acc[rt][ct] = __builtin_amdgcn_mfma_f32_16x16x32_f16(ah[rt], bl, acc[rt][ct], 0, 0, 0);
            }
        }
    }

    // C layout: col = l&15, row = quad*4 + reg
    #pragma unroll
    for (int rt = 0; rt < 2; rt++) {
        #pragma unroll
        for (int r = 0; r < 4; r++) {
            int grow = row0 + w * 32 + rt * 16 + quad * 4 + r;
            if (grow < N) {
                float s = srow[grow];
                #pragma unroll
                for (int ct = 0; ct < 8; ct++)
                    Y[(size_t)grow * 128 + ct * 16 + m] = (_Float16)(acc[rt][ct][r] * s);
            }
        }
    }
}

// ---------------------------------------------------------------- MFMA GEMM, fp16 input (exact: 2 terms)
__global__ __launch_bounds__(256) void gemm_mfma_f16(const _Float16* __restrict__ Xh,
                                                     const _Float16* __restrict__ Whi,
                                                     const _Float16* __restrict__ Wlo,
                                                     const float* __restrict__ srow,
                                                     _Float16* __restrict__ Y, int N)
{
    const int tid = threadIdx.x;
    const int l = tid & 63, w = tid >> 6;
    const int quad = l >> 4, m = l & 15;
    const int row0 = blockIdx.x * 128;
    const half8* Bh = reinterpret_cast<const half8*>(Whi);
    const half8* Bl = reinterpret_cast<const half8*>(Wlo);

    f32x4 acc[2][8] = {};

    for (int kc = 0; kc < 4; kc++) {
        half8 a[2];
        #pragma unroll
        for (int rt = 0; rt < 2; rt++) {
            int grow = row0 + w * 32 + rt * 16 + m;
            half8 z = {};
            a[rt] = (grow < N)
                ? *reinterpret_cast<const half8*>(Xh + (size_t)grow * 128 + kc * 32 + quad * 8)
                : z;
        }
        #pragma unroll
        for (int ct = 0; ct < 8; ct++) {
            int f = kc * 8 + ct;
            half8 bh = Bh[f * 64 + l];
            half8 bl = Bl[f * 64 + l];
            #pragma unroll
            for (int rt = 0; rt < 2; rt++) {
                acc[rt][ct] = __builtin_amdgcn_mfma_f32_16x16x32_f16(a[rt], bh, acc[rt][ct], 0, 0, 0);
                acc[rt][ct] = __builtin_amdgcn_mfma_f32_16x16x32_f16(a[rt], bl, acc[rt][ct], 0, 0, 0);
            }
        }
    }

    #pragma unroll
    for (int rt = 0; rt < 2; rt++) {
        #pragma unroll
        for (int r = 0; r < 4; r++) {
            int grow = row0 + w * 32 + rt * 16 + quad * 4 + r;
            if (grow < N) {
                float s = srow[grow];
                #pragma unroll
                for (int ct = 0; ct < 8; ct++)
                    Y[(size_t)grow * 128 + ct * 16 + m] = (_Float16)(acc[rt][ct][r] * s);
            }
        }
    }
}

// ---------------------------------------------------------------- gather-aggregate (layer 1)
// one wave per node, unroll-8 with zero-row padding (row N_NODES of Hh must be 0):
// Yh[n] = fp16( relu( (sum_{e} Hh[col[e]]) * sin_[n] + bias ) )
__global__ __launch_bounds__(256) void gather_agg(const __half* __restrict__ Hh,
                                                  const int* __restrict__ row_ptr,
                                                  const int* __restrict__ col,
                                                  const float* __restrict__ sin_,
                                                  const float* __restrict__ bias,
                                                  __half* __restrict__ Yh, int N)
{
    int node = blockIdx.x * 4 + (threadIdx.x >> 6);
    if (node >= N) return;
    int lane = threadIdx.x & 63;
    int beg = row_ptr[node], end = row_ptr[node + 1];
    const __half2* H2 = reinterpret_cast<const __half2*>(Hh);
    float2 acc = make_float2(0.f, 0.f);
    for (int i = beg; i < end; i += 8) {
        int c[8];
        #pragma unroll
        for (int j = 0; j < 8; j++)
            c[j] = (i + j < end) ? col[i + j] : N_NODES;   // pad -> zero row
        __half2 v[8];
        #pragma unroll
        for (int j = 0; j < 8; j++)
            v[j] = H2[(c[j] << 6) | lane];                 // 8 loads in flight
        #pragma unroll
        for (int j = 0; j < 8; j++) {
            float2 f = __half22float2(v[j]);
            acc.x += f.x; acc.y += f.y;
        }
    }
    float sc = sin_[node];
    float2 b = reinterpret_cast<const float2*>(bias)[lane];
    float ox = fmaxf(acc.x * sc + b.x, 0.f);
    float oy = fmaxf(acc.y * sc + b.y, 0.f);
    reinterpret_cast<__half2*>(Yh)[(node << 6) | lane] = __floats2half2_rn(ox, oy);
}

// ---------------------------------------------------------------- gather + classifier (layer 2 fused)
// h2 = relu(agg*sc + b2) held per-lane (2 cols); logits = wave-reduce(h2 . Wc) + bc
__global__ __launch_bounds__(256) void gather_cls(const __half* __restrict__ Hh,
                                                  const int* __restrict__ row_ptr,
                                                  const int* __restrict__ col,
                                                  const float* __restrict__ sin_,
                                                  const float* __restrict__ bias,
                                                  const float* __restrict__ Wc,
                                                  const float* __restrict__ bc,
                                                  float* __restrict__ out, int N)
{
    __shared__ float4 WcS[128];   // row k -> 4 class weights
    for (int t = threadIdx.x; t < 128; t += 256)
        WcS[t] = reinterpret_cast<const float4*>(Wc)[t];
    __syncthreads();

    int node = blockIdx.x * 4 + (threadIdx.x >> 6);
    if (node >= N) return;
    int lane = threadIdx.x & 63;
    int beg = row_ptr[node], end = row_ptr[node + 1];
    const __half2* H2 = reinterpret_cast<const __half2*>(Hh);
    float2 acc = make_float2(0.f, 0.f);
    for (int i = beg; i < end; i += 8) {
        int c[8];
        #pragma unroll
        for (int j = 0; j < 8; j++)
            c[j] = (i + j < end) ? col[i + j] : N_NODES;
        __half2 v[8];
        #pragma unroll
        for (int j = 0; j < 8; j++)
            v[j] = H2[(c[j] << 6) | lane];
        #pragma unroll
        for (int j = 0; j < 8; j++) {
            float2 f = __half22float2(v[j]);
            acc.x += f.x; acc.y += f.y;
        }
    }
    float sc = sin_[node];
    float2 b = reinterpret_cast<const float2*>(bias)[lane];
    float ox = fmaxf(acc.x * sc + b.x, 0.f);
    float oy = fmaxf(acc.y * sc + b.y, 0.f);

    float4 wa = WcS[2 * lane], wb = WcS[2 * lane + 1];
    float4 p;
    p.x = ox * wa.x + oy * wb.x;
    p.y = ox * wa.y + oy * wb.y;
    p.z = ox * wa.z + oy * wb.z;
    p.w = ox * wa.w + oy * wb.w;
    #pragma unroll
    for (int off = 1; off < 64; off <<= 1) {
        p.x += __shfl_xor(p.x, off, 64);
        p.y += __shfl_xor(p.y, off, 64);
        p.z += __shfl_xor(p.z, off, 64);
        p.w += __shfl_xor(p.w, off, 64);
    }
    if (lane == 0) {
        float4 r = reinterpret_cast<const float4*>(bc)[0];
        r.x += p.x; r.y += p.y; r.z += p.z; r.w += p.w;
        reinterpret_cast<float4*>(out)[node] = r;
    }
}

// ---------------------------------------------------------------- launch
extern "C" void kernel_launch(void* const* d_in, const int* in_sizes, int n_in,
                              void* d_out, int out_size, void* d_ws, size_t ws_size,
                              hipStream_t stream)
{
    const float* features = (const float*)d_in[0];
    const int*   src      = (const int*)d_in[1];
    const int*   dst      = (const int*)d_in[2];
    const float* W1       = (const float*)d_in[3];
    const float* b1       = (const float*)d_in[4];
    const float* W2       = (const float*)d_in[5];
    const float* b2       = (const float*)d_in[6];
    const float* Wc       = (const float*)d_in[7];
    const float* bc       = (const float*)d_in[8];
    float* out = (float*)d_out;

    char* ws = (char*)d_ws;
    const size_t MB = 1 << 20;
    int* totD  = (int*)(ws + 0);
    int* totS  = (int*)(ws + 1024);
    int* baseD = (int*)(ws + 2048);
    int* baseS = (int*)(ws + 3072);
    int* curD  = (int*)(ws + 4096);
    int* curS  = (int*)(ws + 5120);
    float* sout    = (float*)(ws + 1 * MB);          // N floats
    float* sin_    = (float*)(ws + 2 * MB);          // N floats
    int*   row_ptr = (int*)(ws + 3 * MB);            // N+1 ints
    int*   col     = (int*)(ws + 4 * MB);            // E ints (6.4 MB)
    int2*  bukD    = (int2*)(ws + 11 * MB);          // E pairs (12.8 MB) — dead after csr_bucket
    int*   bukS    = (int*)(ws + 24 * MB);           // E ints (6.4 MB)  — dead after deg_bucket
    _Float16* Whi1 = (_Float16*)(ws + 31 * MB);              // 32 KB
    _Float16* Wlo1 = (_Float16*)(ws + 31 * MB + 32 * 1024);  // 32 KB
    _Float16* Whi2 = (_Float16*)(ws + 31 * MB + 64 * 1024);  // 32 KB
    _Float16* Wlo2 = (_Float16*)(ws + 31 * MB + 96 * 1024);  // 32 KB
    _Float16* hMsg = (_Float16*)(ws + 32 * MB);      // [N+1,128] fp16 (25.6 MB + 256 B)
    _Float16* hA   = (_Float16*)(ws + 58 * MB);      // [N,128] fp16 (25.6 MB)

    const int N = N_NODES;
    const int GBLK = (N + 127) / 128;                // 782

    // ---- CSR build + degree norms (bucket counting sort)
    hipMemsetAsync(ws, 0, 2048, stream);             // totD, totS
    hipMemsetAsync(hMsg + (size_t)N * F, 0, F * sizeof(_Float16), stream);  // zero pad row
    hist_buckets<<<392, 256, 0, stream>>>(src, dst, totD, totS);
    scan_buckets<<<1, 256, 0, stream>>>(totD, totS, baseD, baseS, curD, curS);
    partition<<<256, 512, 0, stream>>>(src, dst, curD, curS, bukD, bukS);
    csr_bucket<<<NBUK, 512, 0, stream>>>(bukD, baseD, row_ptr, sin_, col);
    deg_bucket<<<NBUK, 512, 0, stream>>>(bukS, baseS, sout);

    // ---- pack weights into MFMA B-fragment order (fp16 hi/lo)
    pack_w<<<64, 256, 0, stream>>>(W1, Whi1, Wlo1);
    pack_w<<<64, 256, 0, stream>>>(W2, Whi2, Wlo2);

    // ---- layer 1
    gemm_mfma_f32<<<GBLK, 256, 0, stream>>>(features, Whi1, Wlo1, sout, hMsg, N);
    gather_agg<<<(N + 3) / 4, 256, 0, stream>>>((const __half*)hMsg, row_ptr, col, sin_, b1, (__half*)hA, N);

    // ---- layer 2 (+ fused classifier)
    gemm_mfma_f16<<<GBLK, 256, 0, stream>>>(hA, Whi2, Wlo2, sout, hMsg, N);
    gather_cls<<<(N + 3) / 4, 256, 0, stream>>>((const __half*)hMsg, row_ptr, col, sin_, b2, Wc, bc, out, N);
}